// Round 3
// baseline (4664.630 us; speedup 1.0000x reference)
//
#include <hip/hip_runtime.h>

#define B_    256
#define T_    200
#define C_    512
#define H_    8
#define HEAD_ 64
#define M_    (B_ * T_)          // 51200 rows
#define POS_OUT_ (M_ * C_)       // 26,214,400
#define CHUNK_B_ 32
#define CHUNK_M_ (CHUNK_B_ * T_) // 6400 rows per chunk

// ---------------------------------------------------------------- gather + half-shift
// x[bt,c] = (c<256) ? (t==0 ? 0 : emb[log[bt-1], c]) : emb[log[bt], c]
// logs is pre-offset to the chunk base; bt is chunk-local.
__global__ __launch_bounds__(256) void gather_shift_k(
    const float* __restrict__ emb, const int* __restrict__ logs,
    float* __restrict__ x)
{
    int bt = blockIdx.x;
    int t  = bt % T_;
    int tid = threadIdx.x;
    int id_cur = logs[bt];
    float* xr = x + (size_t)bt * C_;
    xr[256 + tid] = emb[(size_t)id_cur * C_ + 256 + tid];
    if (t == 0) {
        xr[tid] = 0.0f;
    } else {
        int id_prev = logs[bt - 1];
        xr[tid] = emb[(size_t)id_prev * C_ + tid];
    }
}

// ---------------------------------------------------------------- fused QKV GEMM (NT)
// out[m,n] = sum_k x[m,k] * W[n,k] + bias[n];  x fp32 (CHUNK_M,512), W fp32 (512,512)
__global__ __launch_bounds__(256) void gemm_qkv_k(
    const float* __restrict__ x,
    const float* __restrict__ Wq, const float* __restrict__ bq,
    const float* __restrict__ Wk, const float* __restrict__ bk,
    const float* __restrict__ Wv, const float* __restrict__ bv,
    float* __restrict__ q, float* __restrict__ k, float* __restrict__ v)
{
    int nb = blockIdx.x;          // 0..23
    int which = nb >> 3;
    int n0 = (nb & 7) * 64;
    int m0 = blockIdx.y * 64;
    const float* W    = (which == 0) ? Wq : (which == 1) ? Wk : Wv;
    const float* bias = (which == 0) ? bq : (which == 1) ? bk : bv;
    float* dst        = (which == 0) ? q  : (which == 1) ? k  : v;

    __shared__ float As[16][65];
    __shared__ float Bs[16][65];
    int tid  = threadIdx.x;
    int lrow = tid >> 2;
    int lk4  = (tid & 3) * 4;
    int tx = tid & 15, ty = tid >> 4;
    float acc[4][4] = {};

    for (int k0 = 0; k0 < 512; k0 += 16) {
        float4 a4 = *(const float4*)(x + (size_t)(m0 + lrow) * 512 + k0 + lk4);
        float4 b4 = *(const float4*)(W + (size_t)(n0 + lrow) * 512 + k0 + lk4);
        As[lk4 + 0][lrow] = a4.x; As[lk4 + 1][lrow] = a4.y;
        As[lk4 + 2][lrow] = a4.z; As[lk4 + 3][lrow] = a4.w;
        Bs[lk4 + 0][lrow] = b4.x; Bs[lk4 + 1][lrow] = b4.y;
        Bs[lk4 + 2][lrow] = b4.z; Bs[lk4 + 3][lrow] = b4.w;
        __syncthreads();
#pragma unroll
        for (int kk = 0; kk < 16; ++kk) {
            float a[4], bb[4];
#pragma unroll
            for (int i = 0; i < 4; ++i) a[i]  = As[kk][ty * 4 + i];
#pragma unroll
            for (int j = 0; j < 4; ++j) bb[j] = Bs[kk][tx * 4 + j];
#pragma unroll
            for (int i = 0; i < 4; ++i)
#pragma unroll
                for (int j = 0; j < 4; ++j) acc[i][j] += a[i] * bb[j];
        }
        __syncthreads();
    }
#pragma unroll
    for (int i = 0; i < 4; ++i) {
        int row = m0 + ty * 4 + i;
#pragma unroll
        for (int j = 0; j < 4; ++j) {
            int col = n0 + tx * 4 + j;
            dst[(size_t)row * 512 + col] = acc[i][j] + bias[col];
        }
    }
}

// ---------------------------------------------------------------- RoPE in place on q,k
__global__ __launch_bounds__(128) void rope_k(float* __restrict__ q, float* __restrict__ k)
{
    int bt = blockIdx.x;
    int t  = bt % T_;
    int tid = threadIdx.x;      // 0..127
    int h = tid >> 4;
    int j = tid & 15;
    float invf = powf(10000.0f, -(float)j / 16.0f);
    float ang  = (float)t * invf;
    float c = cosf(ang), s = sinf(ang);
    float* qr = q + (size_t)bt * 512 + h * 64;
    float* kr = k + (size_t)bt * 512 + h * 64;
    float a0 = qr[j], b0 = qr[j + 16];
    qr[j]      = a0 * c - b0 * s;
    qr[j + 16] = b0 * c + a0 * s;
    float a1 = kr[j], b1 = kr[j + 16];
    kr[j]      = a1 * c - b1 * s;
    kr[j + 16] = b1 * c + a1 * s;
}

// ---------------------------------------------------------------- fused attention per (b,t)  [chunk-local]
__global__ __launch_bounds__(256) void attn_k(
    const float* __restrict__ q, const float* __restrict__ k, const float* __restrict__ v,
    const float* __restrict__ tw, const float* __restrict__ ta,
    const float* __restrict__ tb, const float* __restrict__ wmix,
    float* __restrict__ out)
{
    int bt = blockIdx.x;
    int b  = bt / T_;
    int t  = bt % T_;
    int tid = threadIdx.x;

    __shared__ float qs[512];
    __shared__ float sc[8][201];
    __shared__ float pm[8][201];
    __shared__ float mixs[64];

    const float* qrow = q + (size_t)bt * 512;
    qs[tid] = qrow[tid];
    qs[tid + 256] = qrow[tid + 256];
    if (tid < 64) mixs[tid] = wmix[tid];
    __syncthreads();

    // scores[g][s] = q[b,t,g,:].k[b,s,g,:] / 8
    const float scale = 0.125f;
    for (int g = 0; g < 8; ++g) {
        for (int s = tid; s <= t; s += 256) {
            const float* krow = k + ((size_t)(b * T_ + s) * 8 + g) * 64;
            float acc = 0.f;
#pragma unroll
            for (int d = 0; d < 64; d += 4) {
                float4 k4 = *(const float4*)(krow + d);
                acc += qs[g * 64 + d]     * k4.x + qs[g * 64 + d + 1] * k4.y
                     + qs[g * 64 + d + 2] * k4.z + qs[g * 64 + d + 3] * k4.w;
            }
            sc[g][s] = acc * scale;
        }
    }
    __syncthreads();

    // softmax per head (8 groups of 32 lanes), then * w
    {
        int g = tid >> 5;
        int lane = tid & 31;
        float m = -INFINITY;
        for (int s = lane; s <= t; s += 32) m = fmaxf(m, sc[g][s]);
#pragma unroll
        for (int off = 16; off >= 1; off >>= 1) m = fmaxf(m, __shfl_xor(m, off));
        float sum = 0.f;
        for (int s = lane; s <= t; s += 32) {
            float e = expf(sc[g][s] - m);
            sc[g][s] = e;
            sum += e;
        }
#pragma unroll
        for (int off = 16; off >= 1; off >>= 1) sum += __shfl_xor(sum, off);
        float inv = 1.0f / sum;
        float betag = tb[g * 200 + t];
        for (int s = lane; s <= t; s += 32) {
            float wv = tw[g * 200 + (199 - (t - s))] * ta[g * 200 + s] * betag;
            sc[g][s] = sc[g][s] * inv * wv;
        }
    }
    __syncthreads();

    // head mix: pm[h][s] = sum_g mix[h,g] * sc[g][s]
    for (int h = 0; h < 8; ++h) {
        for (int s = tid; s <= t; s += 256) {
            float acc = 0.f;
#pragma unroll
            for (int g = 0; g < 8; ++g) acc += mixs[h * 8 + g] * sc[g][s];
            pm[h][s] = acc;
        }
    }
    __syncthreads();

    // out[h,d] = sum_s pm[h][s] * v[b,s,h,d]
    int h1 = tid >> 6, d1 = tid & 63;
    int h2 = h1 + 4;
    float acc1 = 0.f, acc2 = 0.f;
    for (int s = 0; s <= t; ++s) {
        const float* vrow = v + (size_t)(b * T_ + s) * 512;
        acc1 += pm[h1][s] * vrow[h1 * 64 + d1];
        acc2 += pm[h2][s] * vrow[h2 * 64 + d1];
    }
    float* orow = out + (size_t)bt * 512;
    orow[tid]       = acc1;
    orow[tid + 256] = acc2;
}

// ---------------------------------------------------------------- out projection (NT) * gamma
__global__ __launch_bounds__(256) void gemm_out_k(
    const float* __restrict__ A,                 // attn out (CHUNK_M,512) fp32
    const float* __restrict__ Wo, const float* __restrict__ bo,
    const float* __restrict__ gamma,             // (200,)
    float* __restrict__ dst)
{
    int n0 = blockIdx.x * 64;
    int m0 = blockIdx.y * 64;
    __shared__ float As[16][65];
    __shared__ float Bs[16][65];
    int tid  = threadIdx.x;
    int lrow = tid >> 2;
    int lk4  = (tid & 3) * 4;
    int tx = tid & 15, ty = tid >> 4;
    float acc[4][4] = {};

    for (int k0 = 0; k0 < 512; k0 += 16) {
        float4 a4 = *(const float4*)(A  + (size_t)(m0 + lrow) * 512 + k0 + lk4);
        float4 b4 = *(const float4*)(Wo + (size_t)(n0 + lrow) * 512 + k0 + lk4);
        As[lk4 + 0][lrow] = a4.x; As[lk4 + 1][lrow] = a4.y;
        As[lk4 + 2][lrow] = a4.z; As[lk4 + 3][lrow] = a4.w;
        Bs[lk4 + 0][lrow] = b4.x; Bs[lk4 + 1][lrow] = b4.y;
        Bs[lk4 + 2][lrow] = b4.z; Bs[lk4 + 3][lrow] = b4.w;
        __syncthreads();
#pragma unroll
        for (int kk = 0; kk < 16; ++kk) {
            float a[4], bb[4];
#pragma unroll
            for (int i = 0; i < 4; ++i) a[i]  = As[kk][ty * 4 + i];
#pragma unroll
            for (int j = 0; j < 4; ++j) bb[j] = Bs[kk][tx * 4 + j];
#pragma unroll
            for (int i = 0; i < 4; ++i)
#pragma unroll
                for (int j = 0; j < 4; ++j) acc[i][j] += a[i] * bb[j];
        }
        __syncthreads();
    }
#pragma unroll
    for (int i = 0; i < 4; ++i) {
        int row = m0 + ty * 4 + i;
        float g = gamma[row % T_];
#pragma unroll
        for (int j = 0; j < 4; ++j) {
            int col = n0 + tx * 4 + j;
            dst[(size_t)row * 512 + col] = (acc[i][j] + bo[col]) * g;
        }
    }
}

// ---------------------------------------------------------------- pos/neg logits  [chunk-local lf, global out]
__global__ __launch_bounds__(256) void logits_k(
    const float* __restrict__ lf, const float* __restrict__ emb,
    const int* __restrict__ pos, const int* __restrict__ neg,
    float* __restrict__ out, int bt0)
{
    int bt = blockIdx.x;          // chunk-local
    int tid = threadIdx.x;
    const float* l = lf + (size_t)bt * 512;
    const float* pe = emb + (size_t)pos[bt] * 512;
    const float* ne = emb + (size_t)neg[bt] * 512;
    float* po = out + (size_t)(bt0 + bt) * 512;
    float nacc = 0.f;
#pragma unroll
    for (int rep = 0; rep < 2; ++rep) {
        int i = tid + rep * 256;
        float lv = l[i];
        po[i] = lv * pe[i];
        nacc += lv * ne[i];
    }
    __shared__ float rbuf[4];
#pragma unroll
    for (int off = 32; off >= 1; off >>= 1) nacc += __shfl_xor(nacc, off);
    if ((tid & 63) == 0) rbuf[tid >> 6] = nacc;
    __syncthreads();
    if (tid == 0) {
        float tot = rbuf[0] + rbuf[1] + rbuf[2] + rbuf[3];
        out[(size_t)POS_OUT_ + bt0 + bt] = tot;
    }
}

// ----------------------------------------------------------------
extern "C" void kernel_launch(void* const* d_in, const int* in_sizes, int n_in,
                              void* d_out, int out_size, void* d_ws, size_t ws_size,
                              hipStream_t stream)
{
    const int* logs = (const int*)d_in[1];
    const int* pos  = (const int*)d_in[2];
    const int* neg  = (const int*)d_in[3];
    const float* emb = (const float*)d_in[4];
    const float* tw  = (const float*)d_in[5];
    const float* ta  = (const float*)d_in[6];
    const float* tb  = (const float*)d_in[7];
    const float* tg  = (const float*)d_in[8];
    const float* Wq  = (const float*)d_in[9];
    const float* bq  = (const float*)d_in[10];
    const float* Wk  = (const float*)d_in[11];
    const float* bk  = (const float*)d_in[12];
    const float* Wv  = (const float*)d_in[13];
    const float* bv  = (const float*)d_in[14];
    const float* wmix= (const float*)d_in[15];
    const float* Wo  = (const float*)d_in[16];
    const float* bo  = (const float*)d_in[17];

    // Chunked over batch: peak ws = 5 * 13.11 MB = 65.5 MB (all fp32).
    char* ws = (char*)d_ws;
    const size_t SZ_F = (size_t)CHUNK_M_ * C_ * 4;   // 13,107,200
    float* x  = (float*)ws;
    float* q  = (float*)(ws + SZ_F);
    float* k  = (float*)(ws + 2 * SZ_F);
    float* v  = (float*)(ws + 3 * SZ_F);
    float* ao = (float*)(ws + 4 * SZ_F);
    float* lf = q;   // q dead after attention; reuse

    for (int c = 0; c < B_ / CHUNK_B_; ++c) {
        int bt0 = c * CHUNK_M_;
        gather_shift_k<<<CHUNK_M_, 256, 0, stream>>>(emb, logs + bt0, x);
        gemm_qkv_k<<<dim3(24, CHUNK_M_ / 64), 256, 0, stream>>>(x, Wq, bq, Wk, bk, Wv, bv, q, k, v);
        rope_k<<<CHUNK_M_, 128, 0, stream>>>(q, k);
        attn_k<<<CHUNK_M_, 256, 0, stream>>>(q, k, v, tw, ta, tb, wmix, ao);
        gemm_out_k<<<dim3(8, CHUNK_M_ / 64), 256, 0, stream>>>(ao, Wo, bo, tg, lf);
        logits_k<<<CHUNK_M_, 256, 0, stream>>>(lf, emb, pos + bt0, neg + bt0, (float*)d_out, bt0);
    }
}

// Round 4
// 3416.543 us; speedup vs baseline: 1.3653x; 1.3653x over previous
//
#include <hip/hip_runtime.h>

#define B_    256
#define T_    200
#define C_    512
#define H_    8
#define HEAD_ 64
#define M_    (B_ * T_)          // 51200 rows
#define POS_OUT_ (M_ * C_)       // 26,214,400
#define CHUNK_B_ 32
#define CHUNK_M_ (CHUNK_B_ * T_) // 6400 rows per chunk
#define QK_ROWS_ 208             // 200 padded to 13*16
#define VT_PAD_  224             // >= 7 k-steps * 32
#define P_PAD_   232             // LDS row stride (bytes 464 ≡ 0 mod 16; ~2-way banks)

typedef __attribute__((ext_vector_type(8))) short bf16x8;
typedef __attribute__((ext_vector_type(4))) float f32x4;

__device__ __forceinline__ float b2f(unsigned short u) {
    union { unsigned int i; float f; } c; c.i = ((unsigned int)u) << 16; return c.f;
}
__device__ __forceinline__ unsigned short f2b(float f) {
    union { float f; unsigned int i; } c; c.f = f;
    unsigned int x = c.i;
    unsigned int lsb = (x >> 16) & 1u;
    x += 0x7fffu + lsb;
    return (unsigned short)(x >> 16);
}

// ---------------------------------------------------------------- gather + half-shift
__global__ __launch_bounds__(256) void gather_shift_k(
    const float* __restrict__ emb, const int* __restrict__ logs,
    float* __restrict__ x)
{
    int bt = blockIdx.x;
    int t  = bt % T_;
    int tid = threadIdx.x;
    int id_cur = logs[bt];
    float* xr = x + (size_t)bt * C_;
    xr[256 + tid] = emb[(size_t)id_cur * C_ + 256 + tid];
    if (t == 0) {
        xr[tid] = 0.0f;
    } else {
        int id_prev = logs[bt - 1];
        xr[tid] = emb[(size_t)id_prev * C_ + tid];
    }
}

// ---------------------------------------------------------------- zero pad regions of Qb/Kb/Vt
__global__ __launch_bounds__(256) void zero_pads_k(
    unsigned short* __restrict__ Qb, unsigned short* __restrict__ Kb,
    unsigned short* __restrict__ Vt)
{
    int bh = blockIdx.x;           // 0..CHUNK_B*8-1
    int tid = threadIdx.x;
    for (int idx = tid; idx < 8 * 64; idx += 256) {        // rows 200..207
        Qb[(size_t)bh * QK_ROWS_ * 64 + 200 * 64 + idx] = 0;
        Kb[(size_t)bh * QK_ROWS_ * 64 + 200 * 64 + idx] = 0;
    }
    for (int idx = tid; idx < 64 * (VT_PAD_ - 200); idx += 256) {  // cols 200..223
        int d = idx / (VT_PAD_ - 200), s = 200 + idx % (VT_PAD_ - 200);
        Vt[(size_t)bh * 64 * VT_PAD_ + (size_t)d * VT_PAD_ + s] = 0;
    }
}

// ---------------------------------------------------------------- fused QKV GEMM (NT) + bias + RoPE + bf16 pack
// Column remap so RoPE pairs (c, c+16) live in one thread:
//   col(tx,j) = (tx&7)*2 + (j&1) + ((j>>1)&1)*16 + (tx>>3)*32
__global__ __launch_bounds__(256) void gemm_qkv_k(
    const float* __restrict__ x,
    const float* __restrict__ Wq, const float* __restrict__ bq,
    const float* __restrict__ Wk, const float* __restrict__ bk,
    const float* __restrict__ Wv, const float* __restrict__ bv,
    unsigned short* __restrict__ Qb, unsigned short* __restrict__ Kb,
    unsigned short* __restrict__ Vt)
{
    int nb = blockIdx.x;          // 0..23
    int which = nb >> 3;
    int h  = nb & 7;
    int n0 = h * 64;
    int m0 = blockIdx.y * 64;
    const float* W    = (which == 0) ? Wq : (which == 1) ? Wk : Wv;
    const float* bias = (which == 0) ? bq : (which == 1) ? bk : bv;

    __shared__ float As[16][65];
    __shared__ float Bs[16][65];
    int tid  = threadIdx.x;
    int lrow = tid >> 2;
    int lk4  = (tid & 3) * 4;
    int tx = tid & 15, ty = tid >> 4;
    int cmap[4];
#pragma unroll
    for (int j = 0; j < 4; ++j)
        cmap[j] = (tx & 7) * 2 + (j & 1) + ((j >> 1) & 1) * 16 + (tx >> 3) * 32;
    float acc[4][4] = {};

    for (int k0 = 0; k0 < 512; k0 += 16) {
        float4 a4 = *(const float4*)(x + (size_t)(m0 + lrow) * 512 + k0 + lk4);
        float4 b4 = *(const float4*)(W + (size_t)(n0 + lrow) * 512 + k0 + lk4);
        As[lk4 + 0][lrow] = a4.x; As[lk4 + 1][lrow] = a4.y;
        As[lk4 + 2][lrow] = a4.z; As[lk4 + 3][lrow] = a4.w;
        Bs[lk4 + 0][lrow] = b4.x; Bs[lk4 + 1][lrow] = b4.y;
        Bs[lk4 + 2][lrow] = b4.z; Bs[lk4 + 3][lrow] = b4.w;
        __syncthreads();
#pragma unroll
        for (int kk = 0; kk < 16; ++kk) {
            float a[4], bb[4];
#pragma unroll
            for (int i = 0; i < 4; ++i) a[i]  = As[kk][ty * 4 + i];
#pragma unroll
            for (int j = 0; j < 4; ++j) bb[j] = Bs[kk][cmap[j]];
#pragma unroll
            for (int i = 0; i < 4; ++i)
#pragma unroll
                for (int j = 0; j < 4; ++j) acc[i][j] += a[i] * bb[j];
        }
        __syncthreads();
    }

    if (which < 2) {
        unsigned short* dst = (which == 0) ? Qb : Kb;
        float sc = (which == 0) ? 0.125f : 1.0f;
        if (tx < 8) {
            // rotary region: this thread holds cols (c0, c0+16) for c0 = tx*2 + b0
#pragma unroll
            for (int b0 = 0; b0 < 2; ++b0) {
                int c0 = tx * 2 + b0;
                float invf = powf(10000.0f, -(float)c0 / 16.0f);
#pragma unroll
                for (int i = 0; i < 4; ++i) {
                    int row = m0 + ty * 4 + i;
                    int bl = row / T_, t = row % T_;
                    float ang = (float)t * invf;
                    float cs = cosf(ang), sn = sinf(ang);
                    float a  = acc[i][b0]     + bias[n0 + c0];
                    float bv = acc[i][b0 + 2] + bias[n0 + c0 + 16];
                    size_t base = ((size_t)(bl * 8 + h) * QK_ROWS_ + t) * 64;
                    dst[base + c0]      = f2b((a * cs - bv * sn) * sc);
                    dst[base + c0 + 16] = f2b((bv * cs + a * sn) * sc);
                }
            }
        } else {
            // passthrough cols 32..63
#pragma unroll
            for (int j = 0; j < 4; ++j) {
                int c = cmap[j];
#pragma unroll
                for (int i = 0; i < 4; ++i) {
                    int row = m0 + ty * 4 + i;
                    int bl = row / T_, t = row % T_;
                    size_t base = ((size_t)(bl * 8 + h) * QK_ROWS_ + t) * 64;
                    dst[base + c] = f2b((acc[i][j] + bias[n0 + c]) * sc);
                }
            }
        }
    } else {
        // V: transpose-store to Vt[b][h][d][s]
        int r0 = m0 + ty * 4;
        int t0 = r0 % T_;
#pragma unroll
        for (int j = 0; j < 4; ++j) {
            int c = cmap[j];
            float bval = bias[n0 + c];
            if (t0 <= 196) {  // 4 rows same b, contiguous s, 8B-aligned
                int bl = r0 / T_;
                ushort4 v4;
                v4.x = f2b(acc[0][j] + bval); v4.y = f2b(acc[1][j] + bval);
                v4.z = f2b(acc[2][j] + bval); v4.w = f2b(acc[3][j] + bval);
                *(ushort4*)(Vt + ((size_t)(bl * 8 + h) * 64 + c) * VT_PAD_ + t0) = v4;
            } else {
#pragma unroll
                for (int i = 0; i < 4; ++i) {
                    int row = r0 + i;
                    int bl = row / T_, s = row % T_;
                    Vt[((size_t)(bl * 8 + h) * 64 + c) * VT_PAD_ + s] = f2b(acc[i][j] + bval);
                }
            }
        }
    }
}

// ---------------------------------------------------------------- fused MFMA attention
// grid (13 t-tiles, CHUNK_B). 4 waves x 2 heads. S=QK^T (MFMA) -> masked softmax
// -> *w -> P to LDS (bf16) -> in-LDS 8x8 head mix -> PV (MFMA) -> ao fp32.
__global__ __launch_bounds__(256) void attn_fused_k(
    const unsigned short* __restrict__ Qb, const unsigned short* __restrict__ Kb,
    const unsigned short* __restrict__ Vt,
    const float* __restrict__ tw, const float* __restrict__ ta,
    const float* __restrict__ tb, const float* __restrict__ wmix,
    float* __restrict__ ao)
{
    int i_tile = blockIdx.x;       // 0..12
    int b      = blockIdx.y;
    int tid  = threadIdx.x;
    int wave = tid >> 6, lane = tid & 63;
    int quad = lane >> 4, l15 = lane & 15;
    int t0   = i_tile * 16;
    int nst  = i_tile + 1;         // s-tiles needed (s <= t0+15)

    __shared__ unsigned short Pt[8][16][P_PAD_];
    __shared__ float mixs[64];

    {   // zero P region (covers masked/pad cols read by PV)
        unsigned int* p = (unsigned int*)&Pt[0][0][0];
        const int nw = 8 * 16 * P_PAD_ / 2;
        for (int idx = tid; idx < nw; idx += 256) p[idx] = 0u;
        if (tid < 64) mixs[tid] = wmix[tid];
    }
    __syncthreads();

    // ---- phase 1: scores + softmax + w, per wave: 2 heads
    for (int hh = 0; hh < 2; ++hh) {
        int g = wave * 2 + hh;
        const unsigned short* Qg = Qb + (size_t)(b * 8 + g) * QK_ROWS_ * 64;
        const unsigned short* Kg = Kb + (size_t)(b * 8 + g) * QK_ROWS_ * 64;
        bf16x8 a0 = *(const bf16x8*)(Qg + (size_t)(t0 + l15) * 64 + quad * 8);
        bf16x8 a1 = *(const bf16x8*)(Qg + (size_t)(t0 + l15) * 64 + quad * 8 + 32);

        f32x4 sf[13];
#pragma unroll
        for (int st = 0; st < 13; ++st) {
            if (st < nst) {
                bf16x8 k0 = *(const bf16x8*)(Kg + (size_t)(st * 16 + l15) * 64 + quad * 8);
                bf16x8 k1 = *(const bf16x8*)(Kg + (size_t)(st * 16 + l15) * 64 + quad * 8 + 32);
                f32x4 c = {0.f, 0.f, 0.f, 0.f};
                c = __builtin_amdgcn_mfma_f32_16x16x32_bf16(a0, k0, c, 0, 0, 0);
                c = __builtin_amdgcn_mfma_f32_16x16x32_bf16(a1, k1, c, 0, 0, 0);
                sf[st] = c;
            }
        }
        // softmax per row: row = quad*4 + r (t = t0+row), col s = st*16 + l15
        float inv[4];
#pragma unroll
        for (int r = 0; r < 4; ++r) {
            int t = t0 + quad * 4 + r;
            float m = -1e30f;
#pragma unroll
            for (int st = 0; st < 13; ++st) if (st < nst) {
                int s = st * 16 + l15;
                if (s <= t) m = fmaxf(m, sf[st][r]);
            }
            m = fmaxf(m, __shfl_xor(m, 1));
            m = fmaxf(m, __shfl_xor(m, 2));
            m = fmaxf(m, __shfl_xor(m, 4));
            m = fmaxf(m, __shfl_xor(m, 8));
            float sum = 0.f;
#pragma unroll
            for (int st = 0; st < 13; ++st) if (st < nst) {
                int s = st * 16 + l15;
                float e = (s <= t) ? __expf(sf[st][r] - m) : 0.f;
                sf[st][r] = e;
                sum += e;
            }
            sum += __shfl_xor(sum, 1);
            sum += __shfl_xor(sum, 2);
            sum += __shfl_xor(sum, 4);
            sum += __shfl_xor(sum, 8);
            inv[r] = 1.0f / sum;
        }
        // * w  and store P (bf16) to LDS
#pragma unroll
        for (int st = 0; st < 13; ++st) if (st < nst) {
            int s = st * 16 + l15;
            int sc_ = min(s, 199);
            float tav = ta[g * 200 + sc_];
#pragma unroll
            for (int r = 0; r < 4; ++r) {
                int t = t0 + quad * 4 + r;
                bool valid = (s <= t);
                float val = 0.f;
                if (valid) {
                    int wi = 199 - (t - s);
                    wi = wi < 0 ? 0 : wi;
                    int tc = min(t, 199);
                    val = sf[st][r] * inv[r] * (tw[g * 200 + wi] * tav * tb[g * 200 + tc]);
                }
                Pt[g][quad * 4 + r][s] = f2b(val);
            }
        }
    }
    __syncthreads();

    // ---- phase 2: in-place 8x8 head mix over valid s range
    int smax = nst * 16;
    for (int tloc = 0; tloc < 16; ++tloc) {
        if (tid < smax) {
            float pv[8];
#pragma unroll
            for (int g = 0; g < 8; ++g) pv[g] = b2f(Pt[g][tloc][tid]);
#pragma unroll
            for (int ho = 0; ho < 8; ++ho) {
                float o = 0.f;
#pragma unroll
                for (int g = 0; g < 8; ++g) o += mixs[ho * 8 + g] * pv[g];
                Pt[ho][tloc][tid] = f2b(o);
            }
        }
    }
    __syncthreads();

    // ---- phase 3: PV via MFMA, per wave: 2 heads
    int nk = (nst + 1) >> 1;       // k-steps of 32 over s
    for (int hh = 0; hh < 2; ++hh) {
        int hda = wave * 2 + hh;
        const unsigned short* Vh = Vt + (size_t)(b * 8 + hda) * 64 * VT_PAD_;
        f32x4 c4[4];
#pragma unroll
        for (int n = 0; n < 4; ++n) c4[n] = (f32x4){0.f, 0.f, 0.f, 0.f};
#pragma unroll
        for (int ks = 0; ks < 7; ++ks) if (ks < nk) {
            bf16x8 a = *(const bf16x8*)(&Pt[hda][l15][ks * 32 + quad * 8]);
#pragma unroll
            for (int n = 0; n < 4; ++n) {
                bf16x8 bb = *(const bf16x8*)(Vh + (size_t)(n * 16 + l15) * VT_PAD_ + ks * 32 + quad * 8);
                c4[n] = __builtin_amdgcn_mfma_f32_16x16x32_bf16(a, bb, c4[n], 0, 0, 0);
            }
        }
#pragma unroll
        for (int n = 0; n < 4; ++n)
#pragma unroll
            for (int r = 0; r < 4; ++r) {
                int t = t0 + quad * 4 + r;
                if (t < 200)
                    ao[((size_t)(b * T_ + t)) * 512 + hda * 64 + n * 16 + l15] = c4[n][r];
            }
    }
}

// ---------------------------------------------------------------- out projection (NT) * gamma
__global__ __launch_bounds__(256) void gemm_out_k(
    const float* __restrict__ A,
    const float* __restrict__ Wo, const float* __restrict__ bo,
    const float* __restrict__ gamma,
    float* __restrict__ dst)
{
    int n0 = blockIdx.x * 64;
    int m0 = blockIdx.y * 64;
    __shared__ float As[16][65];
    __shared__ float Bs[16][65];
    int tid  = threadIdx.x;
    int lrow = tid >> 2;
    int lk4  = (tid & 3) * 4;
    int tx = tid & 15, ty = tid >> 4;
    float acc[4][4] = {};

    for (int k0 = 0; k0 < 512; k0 += 16) {
        float4 a4 = *(const float4*)(A  + (size_t)(m0 + lrow) * 512 + k0 + lk4);
        float4 b4 = *(const float4*)(Wo + (size_t)(n0 + lrow) * 512 + k0 + lk4);
        As[lk4 + 0][lrow] = a4.x; As[lk4 + 1][lrow] = a4.y;
        As[lk4 + 2][lrow] = a4.z; As[lk4 + 3][lrow] = a4.w;
        Bs[lk4 + 0][lrow] = b4.x; Bs[lk4 + 1][lrow] = b4.y;
        Bs[lk4 + 2][lrow] = b4.z; Bs[lk4 + 3][lrow] = b4.w;
        __syncthreads();
#pragma unroll
        for (int kk = 0; kk < 16; ++kk) {
            float a[4], bb[4];
#pragma unroll
            for (int i = 0; i < 4; ++i) a[i]  = As[kk][ty * 4 + i];
#pragma unroll
            for (int j = 0; j < 4; ++j) bb[j] = Bs[kk][tx * 4 + j];
#pragma unroll
            for (int i = 0; i < 4; ++i)
#pragma unroll
                for (int j = 0; j < 4; ++j) acc[i][j] += a[i] * bb[j];
        }
        __syncthreads();
    }
#pragma unroll
    for (int i = 0; i < 4; ++i) {
        int row = m0 + ty * 4 + i;
        float g = gamma[row % T_];
#pragma unroll
        for (int j = 0; j < 4; ++j) {
            int col = n0 + tx * 4 + j;
            dst[(size_t)row * 512 + col] = (acc[i][j] + bo[col]) * g;
        }
    }
}

// ---------------------------------------------------------------- pos/neg logits
__global__ __launch_bounds__(256) void logits_k(
    const float* __restrict__ lf, const float* __restrict__ emb,
    const int* __restrict__ pos, const int* __restrict__ neg,
    float* __restrict__ out, int bt0)
{
    int bt = blockIdx.x;
    int tid = threadIdx.x;
    const float* l = lf + (size_t)bt * 512;
    const float* pe = emb + (size_t)pos[bt] * 512;
    const float* ne = emb + (size_t)neg[bt] * 512;
    float* po = out + (size_t)(bt0 + bt) * 512;
    float nacc = 0.f;
#pragma unroll
    for (int rep = 0; rep < 2; ++rep) {
        int i = tid + rep * 256;
        float lv = l[i];
        po[i] = lv * pe[i];
        nacc += lv * ne[i];
    }
    __shared__ float rbuf[4];
#pragma unroll
    for (int off = 32; off >= 1; off >>= 1) nacc += __shfl_xor(nacc, off);
    if ((tid & 63) == 0) rbuf[tid >> 6] = nacc;
    __syncthreads();
    if (tid == 0) {
        float tot = rbuf[0] + rbuf[1] + rbuf[2] + rbuf[3];
        out[(size_t)POS_OUT_ + bt0 + bt] = tot;
    }
}

// ----------------------------------------------------------------
extern "C" void kernel_launch(void* const* d_in, const int* in_sizes, int n_in,
                              void* d_out, int out_size, void* d_ws, size_t ws_size,
                              hipStream_t stream)
{
    const int* logs = (const int*)d_in[1];
    const int* pos  = (const int*)d_in[2];
    const int* neg  = (const int*)d_in[3];
    const float* emb = (const float*)d_in[4];
    const float* tw  = (const float*)d_in[5];
    const float* ta  = (const float*)d_in[6];
    const float* tb  = (const float*)d_in[7];
    const float* tg  = (const float*)d_in[8];
    const float* Wq  = (const float*)d_in[9];
    const float* bq  = (const float*)d_in[10];
    const float* Wk  = (const float*)d_in[11];
    const float* bk  = (const float*)d_in[12];
    const float* Wv  = (const float*)d_in[13];
    const float* bv  = (const float*)d_in[14];
    const float* wmix= (const float*)d_in[15];
    const float* Wo  = (const float*)d_in[16];
    const float* bo  = (const float*)d_in[17];

    // ws layout (47.2 MB total, proven ws >= 65.5 MB):
    char* ws = (char*)d_ws;
    const size_t SZ_X  = (size_t)CHUNK_M_ * C_ * 4;                        // 13,107,200
    const size_t SZ_QB = (size_t)CHUNK_B_ * 8 * QK_ROWS_ * 64 * 2;         //  6,815,744
    const size_t SZ_VT = (size_t)CHUNK_B_ * 8 * 64 * VT_PAD_ * 2;          //  7,340,032
    float*          x  = (float*)ws;
    unsigned short* Qb = (unsigned short*)(ws + SZ_X);
    unsigned short* Kb = (unsigned short*)(ws + SZ_X + SZ_QB);
    unsigned short* Vt = (unsigned short*)(ws + SZ_X + 2 * SZ_QB);
    float*          ao = (float*)(ws + SZ_X + 2 * SZ_QB + SZ_VT);
    float*          lf = x;   // x dead after gemm_qkv; reuse

    for (int c = 0; c < B_ / CHUNK_B_; ++c) {
        int bt0 = c * CHUNK_M_;
        gather_shift_k<<<CHUNK_M_, 256, 0, stream>>>(emb, logs + bt0, x);
        zero_pads_k<<<CHUNK_B_ * 8, 256, 0, stream>>>(Qb, Kb, Vt);
        gemm_qkv_k<<<dim3(24, CHUNK_M_ / 64), 256, 0, stream>>>(x, Wq, bq, Wk, bk, Wv, bv, Qb, Kb, Vt);
        attn_fused_k<<<dim3(13, CHUNK_B_), 256, 0, stream>>>(Qb, Kb, Vt, tw, ta, tb, wmix, ao);
        gemm_out_k<<<dim3(8, CHUNK_M_ / 64), 256, 0, stream>>>(ao, Wo, bo, tg, lf);
        logits_k<<<CHUNK_M_, 256, 0, stream>>>(lf, emb, pos + bt0, neg + bt0, (float*)d_out, bt0);
    }
}